// Round 4
// baseline (179.111 us; speedup 1.0000x reference)
//
#include <hip/hip_runtime.h>
#include <hip/hip_bf16.h>

typedef __bf16 bf16;
typedef bf16 bf16x8 __attribute__((ext_vector_type(8)));
typedef _Float16 f16;
typedef f16 f16x8 __attribute__((ext_vector_type(8)));
typedef float f32x4 __attribute__((ext_vector_type(4)));

constexpr int LL = 1024;   // sequence length
constexpr int EE = 512;    // embed dim
constexpr int NBATCH = 8;

__device__ __forceinline__ f32x4 mfma16(bf16x8 a, bf16x8 b, f32x4 c) {
    return __builtin_amdgcn_mfma_f32_16x16x32_bf16(a, b, c, 0, 0, 0);
}

// global -> LDS direct DMA, 16B per lane; LDS dest = wave-uniform base + lane*16.
#define GLOAD_LDS16(g, l)                                                     \
    __builtin_amdgcn_global_load_lds(                                         \
        (const __attribute__((address_space(1))) void*)(g),                   \
        (__attribute__((address_space(3))) void*)(l), 16, 0, 0)

// s_waitcnt immediates (gfx9): vmcnt[3:0]|[15:14], expcnt[6:4], lgkmcnt[11:8]
constexpr int WAIT_VM6_LG0 = 0x076;  // vmcnt(6) lgkmcnt(0)
constexpr int WAIT_VM4_LG0 = 0x074;  // vmcnt(4) lgkmcnt(0)
constexpr int WAIT_VM0_LG0 = 0x070;  // vmcnt(0) lgkmcnt(0)
constexpr int WAIT_LG0     = 0xC07F; // lgkmcnt(0) only (vm/exp no-wait)

// wait-BEFORE-barrier discipline (R1 race fix): lgkm drained with the counted
// vmcnt before s_barrier; sched_barrier(0) pins both sides (rule #18).
template <int IMM>
__device__ __forceinline__ void pipe_barrier() {
    __asm__ volatile("" ::: "memory");
    __builtin_amdgcn_s_waitcnt(IMM);
    __builtin_amdgcn_sched_barrier(0);
    __builtin_amdgcn_s_barrier();
    __builtin_amdgcn_sched_barrier(0);
    __asm__ volatile("" ::: "memory");
}

// 8-phase building blocks (T3+T4+T5 per m201 template):
// phase = { ds_reads; stage; BAR1; lgkm(0); prio1; MFMA; prio0; [vm]; BAR2 }
__device__ __forceinline__ void phase_mid() {
    __asm__ volatile("" ::: "memory");
    __builtin_amdgcn_sched_barrier(0);
    __builtin_amdgcn_s_barrier();                 // BAR1
    __builtin_amdgcn_s_waitcnt(WAIT_LG0);         // my phase reads landed
    __builtin_amdgcn_sched_barrier(0);
    __builtin_amdgcn_s_setprio(1);
    __asm__ volatile("" ::: "memory");
}

template <int VM>  // -1 = no wait
__device__ __forceinline__ void phase_end() {
    __builtin_amdgcn_s_setprio(0);
    __asm__ volatile("" ::: "memory");
    if constexpr (VM >= 0) __builtin_amdgcn_s_waitcnt(VM);
    __builtin_amdgcn_sched_barrier(0);
    __builtin_amdgcn_s_barrier();                 // BAR2
    __builtin_amdgcn_sched_barrier(0);
    __asm__ volatile("" ::: "memory");
}

// ---------------------------------------------------------------------------
// fp32 -> bf16 conversion — weights only (X converts inside proj).
// ---------------------------------------------------------------------------
struct CvtParams {
    const float* src[4];
    bf16* dst[4];
    int n8[4];  // element count / 8
};

__global__ __launch_bounds__(256) void cvt_kernel(CvtParams p) {
    const int y = blockIdx.y;
    const float* __restrict__ src = p.src[y];
    bf16* __restrict__ dst = p.dst[y];
    const int n8 = p.n8[y];
    for (int i = blockIdx.x * 256 + threadIdx.x; i < n8; i += gridDim.x * 256) {
        float4 a = *(const float4*)(src + (size_t)i * 8);
        float4 b = *(const float4*)(src + (size_t)i * 8 + 4);
        bf16x8 o;
        o[0] = (bf16)a.x; o[1] = (bf16)a.y; o[2] = (bf16)a.z; o[3] = (bf16)a.w;
        o[4] = (bf16)b.x; o[5] = (bf16)b.y; o[6] = (bf16)b.z; o[7] = (bf16)b.w;
        *(bf16x8*)(dst + (size_t)i * 8) = o;
    }
}

// ---------------------------------------------------------------------------
// Projection: O[z] = bf16( X[z] @ W[z]^T + b[z] ), 128x256 tile. (unchanged)
// ---------------------------------------------------------------------------
struct ProjParams {
    const float* x[4];
    const bf16* w[4];
    const float* b[4];
};

__global__ __launch_bounds__(256, 2) void proj_kernel(ProjParams p, bf16* __restrict__ outbase) {
    const int f = blockIdx.x;            // 512 blocks
    const int xcd = f & 7;
    const int u = f >> 3;                // 0..63 per XCD
    const int mz = xcd >> 2;             // modality: 0=A, 1=B
    const int by = (xcd & 3) * 16 + (u & 15);   // 0..63 row tile
    const int zq = (u >> 4) & 1;         // q or k projection
    const int bxp = u >> 5;              // 256-col half
    const int z = mz * 2 + zq;

    const float* __restrict__ X = p.x[z];
    const bf16* __restrict__ W = p.w[z];
    const float* __restrict__ Bv = p.b[z];
    bf16* __restrict__ O = outbase + (size_t)z * (NBATCH * LL) * EE;

    __shared__ union {
        struct {
            alignas(16) float Af[2][128][32];   // f32 A tiles
            alignas(16) bf16  Bs[2][256][32];   // bf16 W tiles
        } st;
        alignas(16) bf16 ep[64][264];
    } sm;

    const int t = threadIdx.x;
    const int lane = t & 63, wid = t >> 6;
    const int wm = wid & 1, wn = wid >> 1;
    const int lr = lane & 15, kg = lane >> 4;

    f32x4 acc[4][8] = {};

    const int ar = t >> 3;               // 0..31
    const int ac = t & 7;                // 16B col-group slot
    const int sA = (ar >> 1) & 7;
    const int agc = (ac ^ sA) * 4;
    const float* Xrow0 = X + (size_t)(by * 128 + ar) * EE + agc;

    const int srow = t >> 2;
    const int cgl = t & 3;
    const int gcg = (cgl ^ ((srow >> 1) & 3)) * 8;
    const int scg = (kg ^ ((lr >> 1) & 3)) * 8;
    const bf16* Wrow0 = W + (size_t)(bxp * 256 + srow) * EE + gcg;

    const int cgLo = (2 * kg) ^ ((lr >> 1) & 7);
    const int cgHi = cgLo ^ 1;

    auto stage = [&](int k, int b) {
        const int k0 = k * 32;
#pragma unroll
        for (int i = 0; i < 4; ++i)
            GLOAD_LDS16(Xrow0 + (size_t)(32 * i) * EE + k0, &sm.st.Af[b][32 * i + ar][ac * 4]);
#pragma unroll
        for (int i = 0; i < 4; ++i)
            GLOAD_LDS16(Wrow0 + (size_t)(64 * i) * EE + k0, &sm.st.Bs[b][srow + 64 * i][cgl * 8]);
    };
    auto compute = [&](int b) {
        bf16x8 af[4], bfr[8];
#pragma unroll
        for (int im = 0; im < 4; ++im) {
            const int row = wm * 64 + im * 16 + lr;
            f32x4 lo = *(const f32x4*)&sm.st.Af[b][row][cgLo * 4];
            f32x4 hi = *(const f32x4*)&sm.st.Af[b][row][cgHi * 4];
#pragma unroll
            for (int e = 0; e < 4; ++e) {
                af[im][e] = (bf16)lo[e];
                af[im][4 + e] = (bf16)hi[e];
            }
        }
#pragma unroll
        for (int in = 0; in < 8; ++in)
            bfr[in] = *(const bf16x8*)&sm.st.Bs[b][wn * 128 + in * 16 + lr][scg];
#pragma unroll
        for (int im = 0; im < 4; ++im)
#pragma unroll
            for (int in = 0; in < 8; ++in)
                acc[im][in] = mfma16(af[im], bfr[in], acc[im][in]);
    };

    stage(0, 0);
#pragma unroll
    for (int k = 0; k < 16; ++k) {
        pipe_barrier<WAIT_VM0_LG0>();
        if (k < 15) stage(k + 1, (k + 1) & 1);
        compute(k & 1);
    }
    __syncthreads();

#pragma unroll
    for (int pph = 0; pph < 2; ++pph) {
        if (wm == pph) {
#pragma unroll
            for (int im = 0; im < 4; ++im) {
                const int row = im * 16 + kg * 4;
#pragma unroll
                for (int in = 0; in < 8; ++in) {
                    const int col = wn * 128 + in * 16 + lr;
                    const float bias = Bv[bxp * 256 + col];
#pragma unroll
                    for (int r = 0; r < 4; ++r)
                        sm.ep[row + r][col] = (bf16)(acc[im][in][r] + bias);
                }
            }
        }
        __syncthreads();
#pragma unroll
        for (int i = 0; i < 8; ++i) {
            const int c = i * 256 + t;
            const int row = c >> 5, colg = (c & 31) * 8;
            *(uint4*)(O + (size_t)(by * 128 + pph * 64 + row) * EE + bxp * 256 + colg) =
                *(const uint4*)&sm.ep[row][colg];
        }
        __syncthreads();
    }
}

// ---------------------------------------------------------------------------
// Scores: S = f16( (Q @ K^T) * inv_scale ), 256x256 tile, BK=64, 8 waves.
// R4: 8-phase schedule (T3+T4+T5). All prior structures (R1/R2/R3) pinned at
// MfmaUtil ~27% because {reads -> MFMAs} serialize in lockstep between
// barriers. Here each K-tile runs 4 sub-phases; ds_reads of phase p overlap
// the barrier drain of p-1; staging loads stay in flight across phases with
// ONE counted vmcnt(4) per K-tile (never 0 mid-loop); setprio(1) around the
// pure-MFMA clusters. Schedule hazard proof:
//   stage targets only regions whose last ds_read retired before the
//   preceding BAR2 (A[d] re-staged at p3/p4, reads end p2; B[d^1] staged at
//   p1/p2 while B[d] is read). Certification: tile t+1's newest half is
//   B1(t+1)@p2(t); vmcnt(4) at p4(t) leaves only A0/A1(t+2) (4 loads) in
//   flight => tile t+1 fully landed before its p1 reads.
// LDS 128 KB (2 K-tile dbuf), 1 block/CU. grid 512, XCD swizzle as R3.
// ---------------------------------------------------------------------------
struct ScoresParams {
    const bf16* q[4];
    const bf16* k[4];
    f16* s[4];
};

__global__ __launch_bounds__(512, 2) void scores_kernel(ScoresParams p) {
    const int f = blockIdx.x;        // 512 blocks
    const int xcd = f & 7;
    const int j = f >> 3;            // 0..63 per XCD
    const int z = (xcd << 2) + (j >> 4);
    const int map = z >> 3, n = z & 7;
    const int tile = j & 15;
    const int bx = tile & 3, by = tile >> 2;   // 4x4 grid of 256^2 tiles

    const bf16* __restrict__ Qb = p.q[map] + (size_t)n * LL * EE;
    const bf16* __restrict__ Kb = p.k[map] + (size_t)n * LL * EE;
    f16* __restrict__ Sb = p.s[map] + (size_t)n * LL * LL;

    __shared__ union {
        struct { alignas(16) bf16 A[2][256][64]; alignas(16) bf16 B[2][256][64]; } st;  // 128 KB
        alignas(16) f16 ep[128][264];
    } sm;

    const int t = threadIdx.x;
    const int lane = t & 63, wid = t >> 6;      // 8 waves
    const int wm = wid >> 2, wn = wid & 3;      // 2M x 4N, 128x64 per wave
    const int lr = lane & 15, kg = lane >> 4;
    const int swr = (lr >> 1) & 7;              // read-side row swizzle

    f32x4 acc[8][4] = {};   // 128 VGPRs

    // --- staging map: thread t covers (row chunk + t>>3, group t&7) ---
    const int sr = t >> 3;                      // 0..63
    const int sg = t & 7;
    const int sgsw = sg ^ ((sr >> 1) & 7);      // swizzled source group
    const bf16* Qrow = Qb + (size_t)(by * 256 + sr) * EE + sgsw * 8;
    const bf16* Krow = Kb + (size_t)(bx * 256 + sr) * EE + sgsw * 8;

    // stage one 128-row half-tile (2 x global_load_lds, lane-linear dest)
    auto stageA = [&](int kt, int h) {
        const int d = kt & 1, k0 = kt * 64;
#pragma unroll
        for (int i = 0; i < 2; ++i)
            GLOAD_LDS16(Qrow + (size_t)(h * 128 + i * 64) * EE + k0,
                        &sm.st.A[d][h * 128 + i * 64 + sr][sg * 8]);
    };
    auto stageB = [&](int kt, int h) {
        const int d = kt & 1, k0 = kt * 64;
#pragma unroll
        for (int i = 0; i < 2; ++i)
            GLOAD_LDS16(Krow + (size_t)(h * 128 + i * 64) * EE + k0,
                        &sm.st.B[d][h * 128 + i * 64 + sr][sg * 8]);
    };

    bf16x8 afr0[4][2], afr1[4][2], bfr0[2][2], bfr1[2][2];
    auto readA = [&](int d, int m, bf16x8 (&dst)[4][2]) {
#pragma unroll
        for (int im = 0; im < 4; ++im) {
            const int row = wm * 128 + m * 64 + im * 16 + lr;
#pragma unroll
            for (int s = 0; s < 2; ++s)
                dst[im][s] = *(const bf16x8*)&sm.st.A[d][row][(((s << 2) + kg) ^ swr) * 8];
        }
    };
    auto readB = [&](int d, int nn, bf16x8 (&dst)[2][2]) {
#pragma unroll
        for (int in = 0; in < 2; ++in) {
            const int row = wn * 64 + nn * 32 + in * 16 + lr;
#pragma unroll
            for (int s = 0; s < 2; ++s)
                dst[in][s] = *(const bf16x8*)&sm.st.B[d][row][(((s << 2) + kg) ^ swr) * 8];
        }
    };
    auto mfmaQ = [&](const bf16x8 (&a)[4][2], const bf16x8 (&b)[2][2], int mb, int nb) {
#pragma unroll
        for (int im = 0; im < 4; ++im)
#pragma unroll
            for (int in = 0; in < 2; ++in)
#pragma unroll
                for (int s = 0; s < 2; ++s)
                    acc[mb + im][nb + in] = mfma16(a[im][s], b[in][s], acc[mb + im][nb + in]);
    };

    // prologue: tile0 fully + tile1's A halves; certify tile0 (8 oldest loads)
    stageA(0, 0); stageA(0, 1); stageB(0, 0); stageB(0, 1);
    stageA(1, 0); stageA(1, 1);
    pipe_barrier<WAIT_VM4_LG0>();

    for (int kt = 0; kt < 8; ++kt) {
        const int d = kt & 1;
        // ---- p1: A-M0 + B-N0 reads; stage B0(kt+1) into buf d^1 ----
        readA(d, 0, afr0);
        readB(d, 0, bfr0);
        if (kt < 7) stageB(kt + 1, 0);
        phase_mid();
        mfmaQ(afr0, bfr0, 0, 0);
        phase_end<-1>();
        // ---- p2: A-M1 + B-N1 reads; stage B1(kt+1) ----
        readA(d, 1, afr1);
        readB(d, 1, bfr1);
        if (kt < 7) stageB(kt + 1, 1);
        phase_mid();
        mfmaQ(afr0, bfr1, 0, 2);
        phase_end<-1>();
        // ---- p3: no reads; stage A0(kt+2) into buf d (A reads done @p2) ----
        if (kt < 6) stageA(kt + 2, 0);
        phase_mid();
        mfmaQ(afr1, bfr1, 4, 2);
        phase_end<-1>();
        // ---- p4: no reads; stage A1(kt+2); counted vmcnt certifies kt+1 ----
        if (kt < 6) stageA(kt + 2, 1);
        phase_mid();
        mfmaQ(afr1, bfr0, 4, 0);
        if (kt < 6)       phase_end<WAIT_VM4_LG0>();
        else if (kt == 6) phase_end<WAIT_VM0_LG0>();
        else              phase_end<-1>();
    }
    __syncthreads();

    const float inv_scale = 0.011048543456039806f;  // 1/(4*sqrt(512))
    // Epilogue: two row-half passes; wave wm owns rows wm*128..+127.
#pragma unroll
    for (int pph = 0; pph < 2; ++pph) {
        if (wm == pph) {
#pragma unroll
            for (int mi = 0; mi < 8; ++mi) {
                const int row = mi * 16 + kg * 4;   // mi*16 == m*64+im*16
#pragma unroll
                for (int ni = 0; ni < 4; ++ni) {
                    const int col = wn * 64 + (ni >> 1) * 32 + (ni & 1) * 16 + lr;
#pragma unroll
                    for (int r = 0; r < 4; ++r)
                        sm.ep[row + r][col] = (f16)(acc[mi][ni][r] * inv_scale);
                }
            }
        }
        __syncthreads();
#pragma unroll
        for (int i = 0; i < 8; ++i) {
            const int c = i * 512 + t;                 // 0..4095
            const int row = c >> 5, colg = (c & 31) * 8;
            *(uint4*)(Sb + (size_t)(by * 256 + pph * 128 + row) * LL + bx * 256 + colg) =
                *(const uint4*)&sm.ep[row][colg];
        }
        __syncthreads();
    }
}

// ---------------------------------------------------------------------------
// Row softmax (1024 cols, f16 in) over 8 batches, mean, write one quadrant.
// (unchanged)
// ---------------------------------------------------------------------------
struct SmParams {
    const f16* s[4];
};

__global__ __launch_bounds__(256) void softmax_mean_kernel(SmParams p, float* __restrict__ out) {
    const int map = blockIdx.y;
    const f16* __restrict__ S = p.s[map];
    const int t = threadIdx.x;
    const int half = t >> 7;           // which of the 2 rows
    const int tl = t & 127;            // 0..127 within row
    const int q = blockIdx.x * 2 + half;
    const int lane = t & 63, wid = t >> 6;  // row 0 = waves 0,1; row 1 = waves 2,3
    __shared__ float red[NBATCH][4];

    f16x8 v[NBATCH];
#pragma unroll
    for (int n = 0; n < NBATCH; ++n)
        v[n] = *(const f16x8*)(S + ((size_t)n * LL + q) * LL + tl * 8);

    float e[NBATCH][8];
#pragma unroll
    for (int n = 0; n < NBATCH; ++n) {
        float s = 0.f;
#pragma unroll
        for (int j = 0; j < 8; ++j) {
            e[n][j] = __expf((float)v[n][j]);
            s += e[n][j];
        }
#pragma unroll
        for (int off = 32; off; off >>= 1) s += __shfl_xor(s, off);
        if (lane == 0) red[n][wid] = s;
    }
    __syncthreads();

    float acc[8] = {};
#pragma unroll
    for (int n = 0; n < NBATCH; ++n) {
        const float inv = 0.125f / (red[n][half * 2] + red[n][half * 2 + 1]);
#pragma unroll
        for (int j = 0; j < 8; ++j) acc[j] += e[n][j] * inv;
    }

    const int orow = (map >= 2 ? LL : 0) + q;
    const int ocol = (map & 1 ? LL : 0) + tl * 8;
    float* o = out + (size_t)orow * (2 * LL) + ocol;
    *(float4*)(o + 0) = make_float4(acc[0], acc[1], acc[2], acc[3]);
    *(float4*)(o + 4) = make_float4(acc[4], acc[5], acc[6], acc[7]);
}

// ---------------------------------------------------------------------------
extern "C" void kernel_launch(void* const* d_in, const int* in_sizes, int n_in,
                              void* d_out, int out_size, void* d_ws, size_t ws_size,
                              hipStream_t stream) {
    const float* modalA = (const float*)d_in[0];
    const float* modalB = (const float*)d_in[1];
    const float* WqA = (const float*)d_in[2];
    const float* bqA = (const float*)d_in[3];
    const float* WkA = (const float*)d_in[4];
    const float* bkA = (const float*)d_in[5];
    const float* WqB = (const float*)d_in[6];
    const float* bqB = (const float*)d_in[7];
    const float* WkB = (const float*)d_in[8];
    const float* bkB = (const float*)d_in[9];
    float* out = (float*)d_out;

    const size_t projN = (size_t)(NBATCH * LL) * EE;       // 4 Mi elems
    const size_t mapN = (size_t)NBATCH * LL * LL;          // 8 Mi elems per map
    char* base = (char*)d_ws;
    bf16* qk = (bf16*)base;
    char* region2 = base + 4 * projN * sizeof(bf16);
    bf16* W4 = (bf16*)region2;                              // 4 x 512x512
    f16* S = (f16*)region2;                                 // overlaps W4 (stream-ordered)

    CvtParams cp;
    const float* wsrc[4] = {WqA, WkA, WqB, WkB};
    for (int i = 0; i < 4; ++i) {
        cp.src[i] = wsrc[i];
        cp.dst[i] = W4 + (size_t)i * EE * EE;
        cp.n8[i] = EE * EE / 8;
    }
    cvt_kernel<<<dim3(128, 4), 256, 0, stream>>>(cp);

    ProjParams pp;
    pp.x[0] = modalA; pp.x[1] = modalA; pp.x[2] = modalB; pp.x[3] = modalB;
    for (int i = 0; i < 4; ++i) pp.w[i] = W4 + (size_t)i * EE * EE;
    pp.b[0] = bqA; pp.b[1] = bkA; pp.b[2] = bqB; pp.b[3] = bkB;
    proj_kernel<<<dim3(512), 256, 0, stream>>>(pp, qk);

    const bf16* qA = qk + 0 * projN;
    const bf16* kA = qk + 1 * projN;
    const bf16* qB = qk + 2 * projN;
    const bf16* kB = qk + 3 * projN;

    // map order: 0=(qA,kA)->TL, 1=(qA,kB)->TR, 2=(qB,kB)->BL, 3=(qB,kA)->BR
    ScoresParams sp;
    sp.q[0] = qA; sp.q[1] = qA; sp.q[2] = qB; sp.q[3] = qB;
    sp.k[0] = kA; sp.k[1] = kB; sp.k[2] = kB; sp.k[3] = kA;
    for (int m = 0; m < 4; ++m) sp.s[m] = S + (size_t)m * mapN;
    scores_kernel<<<dim3(512), 512, 0, stream>>>(sp);

    SmParams smp;
    for (int m = 0; m < 4; ++m) smp.s[m] = S + (size_t)m * mapN;
    softmax_mean_kernel<<<dim3(512, 4), 256, 0, stream>>>(smp, out);
}

// Round 6
// 174.307 us; speedup vs baseline: 1.0276x; 1.0276x over previous
//
#include <hip/hip_runtime.h>
#include <hip/hip_bf16.h>

typedef __bf16 bf16;
typedef bf16 bf16x8 __attribute__((ext_vector_type(8)));
typedef _Float16 f16;
typedef f16 f16x8 __attribute__((ext_vector_type(8)));
typedef float f32x4 __attribute__((ext_vector_type(4)));

constexpr int LL = 1024;   // sequence length
constexpr int EE = 512;    // embed dim
constexpr int NBATCH = 8;

__device__ __forceinline__ f32x4 mfma16(bf16x8 a, bf16x8 b, f32x4 c) {
    return __builtin_amdgcn_mfma_f32_16x16x32_bf16(a, b, c, 0, 0, 0);
}

// global -> LDS direct DMA, 16B per lane; LDS dest = wave-uniform base + lane*16.
#define GLOAD_LDS16(g, l)                                                     \
    __builtin_amdgcn_global_load_lds(                                         \
        (const __attribute__((address_space(1))) void*)(g),                   \
        (__attribute__((address_space(3))) void*)(l), 16, 0, 0)

// s_waitcnt immediates (gfx9): vmcnt[3:0]|[15:14], expcnt[6:4], lgkmcnt[11:8]
// wait-BEFORE-barrier discipline (R1 race fix): lgkm + counted vmcnt drained
// before s_barrier; sched_barrier(0) pins both sides (rule #18).
constexpr int WAIT_VM6_LG0 = 0x076;  // vmcnt(6) lgkmcnt(0)
constexpr int WAIT_VM0_LG0 = 0x070;  // vmcnt(0) lgkmcnt(0)

template <int IMM>
__device__ __forceinline__ void pipe_barrier() {
    __asm__ volatile("" ::: "memory");
    __builtin_amdgcn_s_waitcnt(IMM);
    __builtin_amdgcn_sched_barrier(0);   // nothing crosses: pins reads before barrier
    __builtin_amdgcn_s_barrier();
    __builtin_amdgcn_sched_barrier(0);   // pins post-barrier DMAs after barrier
    __asm__ volatile("" ::: "memory");
}

// ---------------------------------------------------------------------------
// fp32 -> bf16 conversion — weights only (X converts inside proj).
// ---------------------------------------------------------------------------
struct CvtParams {
    const float* src[4];
    bf16* dst[4];
    int n8[4];  // element count / 8
};

__global__ __launch_bounds__(256) void cvt_kernel(CvtParams p) {
    const int y = blockIdx.y;
    const float* __restrict__ src = p.src[y];
    bf16* __restrict__ dst = p.dst[y];
    const int n8 = p.n8[y];
    for (int i = blockIdx.x * 256 + threadIdx.x; i < n8; i += gridDim.x * 256) {
        float4 a = *(const float4*)(src + (size_t)i * 8);
        float4 b = *(const float4*)(src + (size_t)i * 8 + 4);
        bf16x8 o;
        o[0] = (bf16)a.x; o[1] = (bf16)a.y; o[2] = (bf16)a.z; o[3] = (bf16)a.w;
        o[4] = (bf16)b.x; o[5] = (bf16)b.y; o[6] = (bf16)b.z; o[7] = (bf16)b.w;
        *(bf16x8*)(dst + (size_t)i * 8) = o;
    }
}

// ---------------------------------------------------------------------------
// Projection: O[z] = bf16( X[z] @ W[z]^T + b[z] ), 128x256 tile. (R1 verified)
// ---------------------------------------------------------------------------
struct ProjParams {
    const float* x[4];
    const bf16* w[4];
    const float* b[4];
};

__global__ __launch_bounds__(256, 2) void proj_kernel(ProjParams p, bf16* __restrict__ outbase) {
    const int f = blockIdx.x;            // 512 blocks
    const int xcd = f & 7;
    const int u = f >> 3;                // 0..63 per XCD
    const int mz = xcd >> 2;             // modality: 0=A, 1=B
    const int by = (xcd & 3) * 16 + (u & 15);   // 0..63 row tile
    const int zq = (u >> 4) & 1;         // q or k projection
    const int bxp = u >> 5;              // 256-col half
    const int z = mz * 2 + zq;

    const float* __restrict__ X = p.x[z];
    const bf16* __restrict__ W = p.w[z];
    const float* __restrict__ Bv = p.b[z];
    bf16* __restrict__ O = outbase + (size_t)z * (NBATCH * LL) * EE;

    __shared__ union {
        struct {
            alignas(16) float Af[2][128][32];   // f32 A tiles
            alignas(16) bf16  Bs[2][256][32];   // bf16 W tiles
        } st;
        alignas(16) bf16 ep[64][264];
    } sm;

    const int t = threadIdx.x;
    const int lane = t & 63, wid = t >> 6;
    const int wm = wid & 1, wn = wid >> 1;
    const int lr = lane & 15, kg = lane >> 4;

    f32x4 acc[4][8] = {};

    const int ar = t >> 3;               // 0..31
    const int ac = t & 7;                // 16B col-group slot
    const int sA = (ar >> 1) & 7;
    const int agc = (ac ^ sA) * 4;
    const float* Xrow0 = X + (size_t)(by * 128 + ar) * EE + agc;

    const int srow = t >> 2;
    const int cgl = t & 3;
    const int gcg = (cgl ^ ((srow >> 1) & 3)) * 8;
    const int scg = (kg ^ ((lr >> 1) & 3)) * 8;
    const bf16* Wrow0 = W + (size_t)(bxp * 256 + srow) * EE + gcg;

    const int cgLo = (2 * kg) ^ ((lr >> 1) & 7);
    const int cgHi = cgLo ^ 1;

    auto stage = [&](int k, int b) {
        const int k0 = k * 32;
#pragma unroll
        for (int i = 0; i < 4; ++i)
            GLOAD_LDS16(Xrow0 + (size_t)(32 * i) * EE + k0, &sm.st.Af[b][32 * i + ar][ac * 4]);
#pragma unroll
        for (int i = 0; i < 4; ++i)
            GLOAD_LDS16(Wrow0 + (size_t)(64 * i) * EE + k0, &sm.st.Bs[b][srow + 64 * i][cgl * 8]);
    };
    auto compute = [&](int b) {
        bf16x8 af[4], bfr[8];
#pragma unroll
        for (int im = 0; im < 4; ++im) {
            const int row = wm * 64 + im * 16 + lr;
            f32x4 lo = *(const f32x4*)&sm.st.Af[b][row][cgLo * 4];
            f32x4 hi = *(const f32x4*)&sm.st.Af[b][row][cgHi * 4];
#pragma unroll
            for (int e = 0; e < 4; ++e) {
                af[im][e] = (bf16)lo[e];
                af[im][4 + e] = (bf16)hi[e];
            }
        }
#pragma unroll
        for (int in = 0; in < 8; ++in)
            bfr[in] = *(const bf16x8*)&sm.st.Bs[b][wn * 128 + in * 16 + lr][scg];
#pragma unroll
        for (int im = 0; im < 4; ++im)
#pragma unroll
            for (int in = 0; in < 8; ++in)
                acc[im][in] = mfma16(af[im], bfr[in], acc[im][in]);
    };

    stage(0, 0);
#pragma unroll
    for (int k = 0; k < 16; ++k) {
        pipe_barrier<WAIT_VM0_LG0>();
        if (k < 15) stage(k + 1, (k + 1) & 1);
        compute(k & 1);
    }
    __syncthreads();

#pragma unroll
    for (int pph = 0; pph < 2; ++pph) {
        if (wm == pph) {
#pragma unroll
            for (int im = 0; im < 4; ++im) {
                const int row = im * 16 + kg * 4;
#pragma unroll
                for (int in = 0; in < 8; ++in) {
                    const int col = wn * 128 + in * 16 + lr;
                    const float bias = Bv[bxp * 256 + col];
#pragma unroll
                    for (int r = 0; r < 4; ++r)
                        sm.ep[row + r][col] = (bf16)(acc[im][in][r] + bias);
                }
            }
        }
        __syncthreads();
#pragma unroll
        for (int i = 0; i < 8; ++i) {
            const int c = i * 256 + t;
            const int row = c >> 5, colg = (c & 31) * 8;
            *(uint4*)(O + (size_t)(by * 128 + pph * 64 + row) * EE + bxp * 256 + colg) =
                *(const uint4*)&sm.ep[row][colg];
        }
        __syncthreads();
    }
}

// ---------------------------------------------------------------------------
// Scores: S = f16( (Q @ K^T) * inv_scale ). 128x256 tiles.
// R6: REGISTER double-buffered fragments + 3 LDS buffers. R1-R4 all pinned at
// ~46-50us because each K-step serialized {ds_read drain -> MFMA} inside every
// wave (lgkm wait on the critical path each step). Here:
//   iter k: vm0+lgkm0 -> barrier -> stage(k+2) -> ds_reads(k+1) [parity regs]
//           -> MFMA(k) [other parity]
// reads(k+1) drain UNDER MFMA(k); iter-top lgkm0 is free; vmcnt(0) waits only
// stage(k+1), issued a full iter (~800cy) earlier -> effectively counted.
// Hazards: wait-before-barrier certifies ALL waves' stage(k+1) before any
// reads(k+1); stage(k+2) hits buffer (k-1)%3 whose reads drained at iter k-1's
// lgkm + barrier. LDS 72KB -> 2 blocks/CU. grid 1024, XCD swizzle as R1.
// ---------------------------------------------------------------------------
struct ScoresParams {
    const bf16* q[4];
    const bf16* k[4];
    f16* s[4];
};

__global__ __launch_bounds__(256, 2) void scores_kernel(ScoresParams p) {
    const int f = blockIdx.x;
    const int xcd = f & 7;
    const int j = f >> 3;            // 0..127 per XCD
    const int z = (xcd << 2) + (j >> 5);
    const int map = z >> 3, n = z & 7;
    const int tile = j & 31;
    const int bxp = tile & 3, by = tile >> 2;

    const bf16* __restrict__ Qb = p.q[map] + (size_t)n * LL * EE;
    const bf16* __restrict__ Kb = p.k[map] + (size_t)n * LL * EE;
    f16* __restrict__ Sb = p.s[map] + (size_t)n * LL * LL;

    __shared__ union {
        struct { alignas(16) bf16 A[3][128][32]; alignas(16) bf16 B[3][256][32]; } st;
        alignas(16) f16 ep[64][264];
    } sm;

    const int t = threadIdx.x;
    const int lane = t & 63, wid = t >> 6;
    const int wm = wid & 1, wn = wid >> 1;
    const int lr = lane & 15, kg = lane >> 4;

    f32x4 acc[4][8] = {};
    bf16x8 af_[2][4], bf_[2][8];   // parity-indexed fragment double-buffer

    const int srow = t >> 2;
    const int cgl = t & 3;
    const int gcg = (cgl ^ ((srow >> 1) & 3)) * 8;
    const int scg = (kg ^ ((lr >> 1) & 3)) * 8;

    const bf16* Qrow0 = Qb + (size_t)(by * 128 + srow) * EE + gcg;
    const bf16* Krow0 = Kb + (size_t)(bxp * 256 + srow) * EE + gcg;

    auto stage = [&](int k, int b) {
        const int k0 = k * 32;
#pragma unroll
        for (int i = 0; i < 2; ++i)
            GLOAD_LDS16(Qrow0 + (size_t)(64 * i) * EE + k0, &sm.st.A[b][srow + 64 * i][cgl * 8]);
#pragma unroll
        for (int i = 0; i < 4; ++i)
            GLOAD_LDS16(Krow0 + (size_t)(64 * i) * EE + k0, &sm.st.B[b][srow + 64 * i][cgl * 8]);
    };

// reads tile-k fragments from LDS buffer b into parity set P (macro keeps the
// parity index a compile-time literal -> registers, not scratch; rule #20)
#define READS(P, b)                                                           \
    do {                                                                      \
        _Pragma("unroll")                                                     \
        for (int im = 0; im < 4; ++im)                                        \
            af_[P][im] = *(const bf16x8*)&sm.st.A[b][wm * 64 + im * 16 + lr][scg]; \
        _Pragma("unroll")                                                     \
        for (int in = 0; in < 8; ++in)                                        \
            bf_[P][in] = *(const bf16x8*)&sm.st.B[b][wn * 128 + in * 16 + lr][scg]; \
    } while (0)

#define COMPUTE(P)                                                            \
    do {                                                                      \
        _Pragma("unroll")                                                     \
        for (int im = 0; im < 4; ++im)                                        \
            _Pragma("unroll")                                                 \
            for (int in = 0; in < 8; ++in)                                    \
                acc[im][in] = mfma16(af_[P][im], bf_[P][in], acc[im][in]);    \
    } while (0)

    // prologue: stage(0),(1); certify stage(0) [6 newest = stage(1)]; reads(0)
    stage(0, 0);
    stage(1, 1);
    pipe_barrier<WAIT_VM6_LG0>();
    READS(0, 0);

#pragma unroll
    for (int k = 0; k < 16; ++k) {
        // vm0: stage(k+1) landed (only outstanding; issued ~1 iter ago).
        // lgkm0: reads(k) drained (issued before MFMA(k-1); drained under it).
        pipe_barrier<WAIT_VM0_LG0>();
        if (k < 14) stage(k + 2, (k + 2) % 3);
        if (k < 15) {
            if ((k & 1) == 0) READS(1, (k + 1) % 3);
            else              READS(0, (k + 1) % 3);
        }
        if ((k & 1) == 0) COMPUTE(0);
        else              COMPUTE(1);
    }
#undef READS
#undef COMPUTE
    __syncthreads();

    const float inv_scale = 0.011048543456039806f;  // 1/(4*sqrt(512))
#pragma unroll
    for (int pph = 0; pph < 2; ++pph) {
        if (wm == pph) {
#pragma unroll
            for (int im = 0; im < 4; ++im) {
                const int row = im * 16 + kg * 4;
#pragma unroll
                for (int in = 0; in < 8; ++in) {
                    const int col = wn * 128 + in * 16 + lr;
#pragma unroll
                    for (int r = 0; r < 4; ++r)
                        sm.ep[row + r][col] = (f16)(acc[im][in][r] * inv_scale);
                }
            }
        }
        __syncthreads();
#pragma unroll
        for (int i = 0; i < 8; ++i) {
            const int c = i * 256 + t;
            const int row = c >> 5, colg = (c & 31) * 8;
            *(uint4*)(Sb + (size_t)(by * 128 + pph * 64 + row) * LL + bxp * 256 + colg) =
                *(const uint4*)&sm.ep[row][colg];
        }
        __syncthreads();
    }
}

// ---------------------------------------------------------------------------
// Row softmax (1024 cols, f16 in) over 8 batches, mean, write one quadrant.
// (R1 verified version)
// ---------------------------------------------------------------------------
struct SmParams {
    const f16* s[4];
};

__global__ __launch_bounds__(256) void softmax_mean_kernel(SmParams p, float* __restrict__ out) {
    const int map = blockIdx.y;
    const f16* __restrict__ S = p.s[map];
    const int t = threadIdx.x;
    const int half = t >> 7;           // which of the 2 rows
    const int tl = t & 127;            // 0..127 within row
    const int q = blockIdx.x * 2 + half;
    const int lane = t & 63, wid = t >> 6;  // row 0 = waves 0,1; row 1 = waves 2,3
    __shared__ float red[NBATCH][4];

    f16x8 v[NBATCH];
#pragma unroll
    for (int n = 0; n < NBATCH; ++n)
        v[n] = *(const f16x8*)(S + ((size_t)n * LL + q) * LL + tl * 8);

    float e[NBATCH][8];
#pragma unroll
    for (int n = 0; n < NBATCH; ++n) {
        float s = 0.f;
#pragma unroll
        for (int j = 0; j < 8; ++j) {
            e[n][j] = __expf((float)v[n][j]);
            s += e[n][j];
        }
#pragma unroll
        for (int off = 32; off; off >>= 1) s += __shfl_xor(s, off);
        if (lane == 0) red[n][wid] = s;
    }
    __syncthreads();

    float acc[8] = {};
#pragma unroll
    for (int n = 0; n < NBATCH; ++n) {
        const float inv = 0.125f / (red[n][half * 2] + red[n][half * 2 + 1]);
#pragma unroll
        for (int j = 0; j < 8; ++j) acc[j] += e[n][j] * inv;
    }

    const int orow = (map >= 2 ? LL : 0) + q;
    const int ocol = (map & 1 ? LL : 0) + tl * 8;
    float* o = out + (size_t)orow * (2 * LL) + ocol;
    *(float4*)(o + 0) = make_float4(acc[0], acc[1], acc[2], acc[3]);
    *(float4*)(o + 4) = make_float4(acc[4], acc[5], acc[6], acc[7]);
}

// ---------------------------------------------------------------------------
extern "C" void kernel_launch(void* const* d_in, const int* in_sizes, int n_in,
                              void* d_out, int out_size, void* d_ws, size_t ws_size,
                              hipStream_t stream) {
    const float* modalA = (const float*)d_in[0];
    const float* modalB = (const float*)d_in[1];
    const float* WqA = (const float*)d_in[2];
    const float* bqA = (const float*)d_in[3];
    const float* WkA = (const float*)d_in[4];
    const float* bkA = (const float*)d_in[5];
    const float* WqB = (const float*)d_in[6];
    const float* bqB = (const float*)d_in[7];
    const float* WkB = (const float*)d_in[8];
    const float* bkB = (const float*)d_in[9];
    float* out = (float*)d_out;

    // ws layout (~100.7 MB):
    //   [qk: 4 x 8192x512 bf16 = 33.55 MB]
    //   [region2: W4 bf16 (2 MB, dead after proj) then reused by S[4] f16 (67.1 MB)]
    const size_t projN = (size_t)(NBATCH * LL) * EE;       // 4 Mi elems
    const size_t mapN = (size_t)NBATCH * LL * LL;          // 8 Mi elems per map
    char* base = (char*)d_ws;
    bf16* qk = (bf16*)base;
    char* region2 = base + 4 * projN * sizeof(bf16);
    bf16* W4 = (bf16*)region2;                              // 4 x 512x512
    f16* S = (f16*)region2;                                 // overlaps W4 (stream-ordered)

    CvtParams cp;
    const float* wsrc[4] = {WqA, WkA, WqB, WkB};
    for (int i = 0; i < 4; ++i) {
        cp.src[i] = wsrc[i];
        cp.dst[i] = W4 + (size_t)i * EE * EE;
        cp.n8[i] = EE * EE / 8;
    }
    cvt_kernel<<<dim3(128, 4), 256, 0, stream>>>(cp);

    ProjParams pp;
    pp.x[0] = modalA; pp.x[1] = modalA; pp.x[2] = modalB; pp.x[3] = modalB;
    for (int i = 0; i < 4; ++i) pp.w[i] = W4 + (size_t)i * EE * EE;
    pp.b[0] = bqA; pp.b[1] = bkA; pp.b[2] = bqB; pp.b[3] = bkB;
    proj_kernel<<<dim3(512), 256, 0, stream>>>(pp, qk);

    const bf16* qA = qk + 0 * projN;
    const bf16* kA = qk + 1 * projN;
    const bf16* qB = qk + 2 * projN;
    const bf16* kB = qk + 3 * projN;

    // map order: 0=(qA,kA)->TL, 1=(qA,kB)->TR, 2=(qB,kB)->BL, 3=(qB,kA)->BR
    ScoresParams sp;
    sp.q[0] = qA; sp.q[1] = qA; sp.q[2] = qB; sp.q[3] = qB;
    sp.k[0] = kA; sp.k[1] = kB; sp.k[2] = kB; sp.k[3] = kA;
    for (int m = 0; m < 4; ++m) sp.s[m] = S + (size_t)m * mapN;
    scores_kernel<<<dim3(1024), 256, 0, stream>>>(sp);

    SmParams smp;
    for (int m = 0; m < 4; ++m) smp.s[m] = S + (size_t)m * mapN;
    softmax_mean_kernel<<<dim3(512, 4), 256, 0, stream>>>(smp, out);
}